// Round 1
// baseline (3614.805 us; speedup 1.0000x reference)
//
#include <hip/hip_runtime.h>
#include <math.h>

// Problem constants (N=80000, Rr=5, A=8, D=32, T=32, K=8 rotations, ROT_DELTA=1)
#define RR 5
#define AA 8
#define DD 32
#define TT 32
#define KK 8
#define MM 1280  // RR*AA*DD

// ---------------------------------------------------------------------------
// Kernel A: barycentric interpolation.  interp[vL, r*8+a, d] =
//   sum_i bc_w[v,r,a,i] * sig[bc_idx[v,r,a,i], d]
// One block per vertex; 256 threads = 8 groups x 32 d-lanes (coalesced gathers).
// ---------------------------------------------------------------------------
__global__ void interp_kernel(const float* __restrict__ sig,
                              const int* __restrict__ bc_idx,
                              const float* __restrict__ bc_w,
                              float* __restrict__ interp,
                              int c0, int len) {
    int vL = blockIdx.x;
    if (vL >= len) return;
    int v = c0 + vL;
    int tid = threadIdx.x;
    int d = tid & 31;
    int g = tid >> 5;  // 0..7
    float* obase = interp + (size_t)vL * MM;
    #pragma unroll
    for (int p = 0; p < 5; ++p) {
        int ra = g + p * 8;              // covers 0..39
        int base = (v * 40 + ra) * 3;
        int i0 = bc_idx[base + 0];
        int i1 = bc_idx[base + 1];
        int i2 = bc_idx[base + 2];
        float w0 = bc_w[base + 0];
        float w1 = bc_w[base + 1];
        float w2 = bc_w[base + 2];
        float val = w0 * sig[(size_t)i0 * 32 + d]
                  + w1 * sig[(size_t)i1 * 32 + d]
                  + w2 * sig[(size_t)i2 * 32 + d];
        obase[ra * 32 + d] = val;
    }
}

// ---------------------------------------------------------------------------
// Kernel B: conv + bias + angular max pool.
// out[v,k,t] = sum_{r,a',d} interp[v,r,(a'+k)&7,d] * W[t,r,a',d] + b[t]
// Block = 256 threads (4 waves), 8 vertices/wave -> 32 vertices/block.
// Lane: vi = lane&7 (vertex), tg = lane>>3 (t-group); lane tile = 8 k x 4 t
// with t = tg + 8*j.  W r-chunk staged in LDS as float4 [(a*8+dc)*33 + t]
// (padded: conflict-free b128 reads).  interp read from global (float4).
// ---------------------------------------------------------------------------
__global__ __launch_bounds__(256, 4)
void conv_kernel(const float* __restrict__ interp,
                 const float* __restrict__ Wg,
                 const float* __restrict__ bias,
                 float* __restrict__ s_out,
                 int c0, int len) {
    __shared__ float Wl[8448];  // ((63*33)+31)*4+4 floats, ~33.8 KB

    int tid = threadIdx.x;
    int lane = tid & 63;
    int wv = tid >> 6;
    int vi = lane & 7;
    int tg = lane >> 3;  // 0..7
    int vLocal = blockIdx.x * 32 + wv * 8 + vi;
    bool valid = vLocal < len;
    int vc = valid ? vLocal : (len - 1);
    const float* ip = interp + (size_t)vc * MM;

    float acc[8][4];
    #pragma unroll
    for (int k = 0; k < 8; ++k)
        #pragma unroll
        for (int j = 0; j < 4; ++j) acc[k][j] = 0.f;

    const float4* Wg4 = (const float4*)Wg;

    for (int r = 0; r < RR; ++r) {
        __syncthreads();
        // stage W[:, r, :, :] -> LDS (coalesced global float4 reads)
        for (int i2 = tid; i2 < 2048; i2 += 256) {
            int t = i2 >> 6;          // 0..31
            int a = (i2 >> 3) & 7;    // 0..7
            int dc = i2 & 7;          // 0..7 (d/4)
            float4 val = Wg4[((t * 5 + r) * 8 + a) * 8 + dc];
            *(float4*)&Wl[((a * 8 + dc) * 33 + t) * 4] = val;
        }
        __syncthreads();

        const float* ipr = ip + r * 256;
        #pragma unroll 1
        for (int d0 = 0; d0 < 32; d0 += 4) {
            float4 irow[8];
            #pragma unroll
            for (int a = 0; a < 8; ++a)
                irow[a] = *(const float4*)&ipr[a * 32 + d0];
            int dc = d0 >> 2;
            #pragma unroll
            for (int ap = 0; ap < 8; ++ap) {
                float4 bf[4];
                #pragma unroll
                for (int j = 0; j < 4; ++j)
                    bf[j] = *(const float4*)&Wl[((ap * 8 + dc) * 33 + (tg + 8 * j)) * 4];
                #pragma unroll
                for (int kk = 0; kk < 8; ++kk) {
                    float4 af = irow[(ap + kk) & 7];
                    #pragma unroll
                    for (int j = 0; j < 4; ++j) {
                        acc[kk][j] = fmaf(af.x, bf[j].x, acc[kk][j]);
                        acc[kk][j] = fmaf(af.y, bf[j].y, acc[kk][j]);
                        acc[kk][j] = fmaf(af.z, bf[j].z, acc[kk][j]);
                        acc[kk][j] = fmaf(af.w, bf[j].w, acc[kk][j]);
                    }
                }
            }
        }
    }

    // bias (included in pooling norm, as in reference)
    float bj[4];
    #pragma unroll
    for (int j = 0; j < 4; ++j) bj[j] = bias[tg + 8 * j];
    #pragma unroll
    for (int k = 0; k < 8; ++k)
        #pragma unroll
        for (int j = 0; j < 4; ++j) acc[k][j] += bj[j];

    // angular max pool: argmax_k ||out[v,k,:]||_2, first-max-wins
    float best = -1.f;
    int bk = 0;
    #pragma unroll
    for (int k = 0; k < 8; ++k) {
        float nl = acc[k][0] * acc[k][0] + acc[k][1] * acc[k][1]
                 + acc[k][2] * acc[k][2] + acc[k][3] * acc[k][3];
        nl += __shfl_xor(nl, 8);
        nl += __shfl_xor(nl, 16);
        nl += __shfl_xor(nl, 32);   // sum over the 8 tg groups (full 32 t's)
        float n = sqrtf(nl);
        if (n > best) { best = n; bk = k; }
    }

    if (valid) {
        float sel0 = 0.f, sel1 = 0.f, sel2 = 0.f, sel3 = 0.f;
        #pragma unroll
        for (int k = 0; k < 8; ++k) {
            if (k == bk) { sel0 = acc[k][0]; sel1 = acc[k][1]; sel2 = acc[k][2]; sel3 = acc[k][3]; }
        }
        int v = c0 + vLocal;
        float* o = s_out + (size_t)v * 32 + tg;
        o[0]  = sel0;
        o[8]  = sel1;
        o[16] = sel2;
        o[24] = sel3;
    }
}

// ---------------------------------------------------------------------------
// Stats: per-column (t) sum and sumsq over N rows, fp64 accumulation.
// ---------------------------------------------------------------------------
__global__ void stats_kernel(const float* __restrict__ s,
                             double* __restrict__ sums,
                             double* __restrict__ sumsq, int n) {
    __shared__ double la[256];
    __shared__ double lb[256];
    int tid = threadIdx.x;
    int t = tid & 31;
    int row = tid >> 5;  // 0..7
    double a = 0.0, b = 0.0;
    for (int v = blockIdx.x * 8 + row; v < n; v += gridDim.x * 8) {
        float x = s[(size_t)v * 32 + t];
        a += (double)x;
        b += (double)x * (double)x;
    }
    la[tid] = a; lb[tid] = b;
    __syncthreads();
    for (int off = 128; off >= 32; off >>= 1) {
        if (tid < off) { la[tid] += la[tid + off]; lb[tid] += lb[tid + off]; }
        __syncthreads();
    }
    if (tid < 32) {
        atomicAdd(&sums[t], la[tid]);
        atomicAdd(&sumsq[t], lb[tid]);
    }
}

// ---------------------------------------------------------------------------
// Finalize BN: scale = gamma * rsqrt(var + eps), shift = beta - mu*scale
// ---------------------------------------------------------------------------
__global__ void finalize_kernel(const double* __restrict__ sums,
                                const double* __restrict__ sumsq,
                                const float* __restrict__ gamma,
                                const float* __restrict__ beta,
                                float* __restrict__ scale,
                                float* __restrict__ shift, int n) {
    int t = threadIdx.x;
    if (t < 32) {
        double mu = sums[t] / (double)n;
        double var = sumsq[t] / (double)n - mu * mu;
        double sc = (double)gamma[t] / sqrt(var + 1e-3);
        scale[t] = (float)sc;
        shift[t] = (float)((double)beta[t] - mu * sc);
    }
}

// ---------------------------------------------------------------------------
// sig2 = relu(scale*s + shift)   (branch 1 epilogue -> conv2 input)
// ---------------------------------------------------------------------------
__global__ void affine_relu_kernel(const float* __restrict__ s,
                                   const float* __restrict__ scale,
                                   const float* __restrict__ shift,
                                   float* __restrict__ o, int n4) {
    int e = blockIdx.x * blockDim.x + threadIdx.x;
    if (e >= n4) return;
    int t0 = (e & 7) * 4;
    float4 x = ((const float4*)s)[e];
    float4 y;
    y.x = fmaxf(fmaf(scale[t0 + 0], x.x, shift[t0 + 0]), 0.f);
    y.y = fmaxf(fmaf(scale[t0 + 1], x.y, shift[t0 + 1]), 0.f);
    y.z = fmaxf(fmaf(scale[t0 + 2], x.z, shift[t0 + 2]), 0.f);
    y.w = fmaxf(fmaf(scale[t0 + 3], x.w, shift[t0 + 3]), 0.f);
    ((float4*)o)[e] = y;
}

// ---------------------------------------------------------------------------
// out = relu(scale*s + shift + signal)   (final residual epilogue)
// ---------------------------------------------------------------------------
__global__ void final_kernel(const float* __restrict__ s,
                             const float* __restrict__ scale,
                             const float* __restrict__ shift,
                             const float* __restrict__ sig,
                             float* __restrict__ o, int n4) {
    int e = blockIdx.x * blockDim.x + threadIdx.x;
    if (e >= n4) return;
    int t0 = (e & 7) * 4;
    float4 x = ((const float4*)s)[e];
    float4 z = ((const float4*)sig)[e];
    float4 y;
    y.x = fmaxf(fmaf(scale[t0 + 0], x.x, shift[t0 + 0]) + z.x, 0.f);
    y.y = fmaxf(fmaf(scale[t0 + 1], x.y, shift[t0 + 1]) + z.y, 0.f);
    y.z = fmaxf(fmaf(scale[t0 + 2], x.z, shift[t0 + 2]) + z.z, 0.f);
    y.w = fmaxf(fmaf(scale[t0 + 3], x.w, shift[t0 + 3]) + z.w, 0.f);
    ((float4*)o)[e] = y;
}

__global__ void zero_stats_kernel(double* __restrict__ d, float* __restrict__ f) {
    int t = threadIdx.x;
    if (t < 128) d[t] = 0.0;
    if (t < 128) f[t] = 0.f;
}

// ---------------------------------------------------------------------------
extern "C" void kernel_launch(void* const* d_in, const int* in_sizes, int n_in,
                              void* d_out, int out_size, void* d_ws, size_t ws_size,
                              hipStream_t stream) {
    const float* signal = (const float*)d_in[0];
    const int* bc_idx   = (const int*)d_in[1];
    const float* bc_w   = (const float*)d_in[2];
    const float* W1     = (const float*)d_in[3];
    const float* b1     = (const float*)d_in[4];
    const float* g1     = (const float*)d_in[5];
    const float* be1    = (const float*)d_in[6];
    const float* W2     = (const float*)d_in[7];
    const float* b2     = (const float*)d_in[8];
    const float* g2     = (const float*)d_in[9];
    const float* be2    = (const float*)d_in[10];
    float* out = (float*)d_out;

    const int N = in_sizes[0] / 32;  // 80000

    char* ws = (char*)d_ws;
    double* sums1  = (double*)ws;         // 32
    double* sumsq1 = sums1 + 32;
    double* sums2  = sums1 + 64;
    double* sumsq2 = sums1 + 96;
    float* scale1 = (float*)(ws + 1024);
    float* shift1 = scale1 + 32;
    float* scale2 = scale1 + 64;
    float* shift2 = scale1 + 96;
    float* s1  = (float*)(ws + 4096);
    float* sg2 = s1 + (size_t)N * 32;
    float* s2  = sg2 + (size_t)N * 32;
    float* interpBuf = s2 + (size_t)N * 32;

    size_t used = 4096 + 3 * (size_t)N * 32 * 4;
    size_t avail = (ws_size > used) ? (ws_size - used) : 0;
    long long ch = (long long)(avail / (MM * 4));
    ch &= ~31LL;
    if (ch > N) ch = N;
    if (ch < 32) ch = 32;  // last-resort guard against zero-progress loop
    int CH = (int)ch;

    zero_stats_kernel<<<1, 128, 0, stream>>>((double*)ws, (float*)(ws + 1024));

    // ---- branch 1: conv -> pool -> (stats) ----
    for (int c0 = 0; c0 < N; c0 += CH) {
        int len = (N - c0 < CH) ? (N - c0) : CH;
        interp_kernel<<<len, 256, 0, stream>>>(signal, bc_idx, bc_w, interpBuf, c0, len);
        conv_kernel<<<(len + 31) / 32, 256, 0, stream>>>(interpBuf, W1, b1, s1, c0, len);
    }
    stats_kernel<<<64, 256, 0, stream>>>(s1, sums1, sumsq1, N);
    finalize_kernel<<<1, 32, 0, stream>>>(sums1, sumsq1, g1, be1, scale1, shift1, N);
    affine_relu_kernel<<<(N * 8 + 255) / 256, 256, 0, stream>>>(s1, scale1, shift1, sg2, N * 8);

    // ---- branch 2: conv -> pool -> (stats) ----
    for (int c0 = 0; c0 < N; c0 += CH) {
        int len = (N - c0 < CH) ? (N - c0) : CH;
        interp_kernel<<<len, 256, 0, stream>>>(sg2, bc_idx, bc_w, interpBuf, c0, len);
        conv_kernel<<<(len + 31) / 32, 256, 0, stream>>>(interpBuf, W2, b2, s2, c0, len);
    }
    stats_kernel<<<64, 256, 0, stream>>>(s2, sums2, sumsq2, N);
    finalize_kernel<<<1, 32, 0, stream>>>(sums2, sumsq2, g2, be2, scale2, shift2, N);

    // ---- residual + relu ----
    final_kernel<<<(N * 8 + 255) / 256, 256, 0, stream>>>(s2, scale2, shift2, signal, out, N * 8);
}

// Round 2
// 1445.282 us; speedup vs baseline: 2.5011x; 2.5011x over previous
//
#include <hip/hip_runtime.h>
#include <math.h>

// Problem constants (N=80000, Rr=5, A=8, D=32, T=32, K=8 rotations, ROT_DELTA=1)
#define RR 5
#define AA 8
#define DD 32
#define TT 32
#define KK 8
#define MM 1280  // RR*AA*DD

// ---------------------------------------------------------------------------
// Fused kernel: barycentric interp (gather) + conv + bias + angular max pool.
// out[v,k,t] = sum_{r,a',d} interp[v,r,(a'+k)&7,d] * W[t,r,a',d] + b[t]
//   interp[v,r,a,d] = sum_i bc_w[v,r,a,i] * sig[bc_idx[v,r,a,i], d]
//
// Block = 256 threads (4 waves), 32 vertices/block.
// Per r-chunk: stage W[:,r,:,:] (32 KB) and interp tile (32 KB) in LDS.
//   Gather phase lanes: d = tid&31 (coalesced 128-B sig rows), q = tid>>5.
//   Compute phase lanes: vi = lane&7 (vertex), tg = lane>>3; per-lane tile
//   8 k x 4 t (t = tg+8j).  Il stride 260 => b128 reads at bank-quad 4*vi:
//   conflict-free.  Wl stride 33 (t) => bank-quad 4*tg: conflict-free.
// ---------------------------------------------------------------------------
__global__ __launch_bounds__(256, 2)
void fused_conv_kernel(const float* __restrict__ sig,
                       const int* __restrict__ bc_idx,
                       const float* __restrict__ bc_w,
                       const float* __restrict__ Wg,
                       const float* __restrict__ bias,
                       float* __restrict__ s_out,
                       int N) {
    __shared__ float Wl[8448];      // ~33.8 KB
    __shared__ float Il[32 * 260];  // ~33.3 KB

    int tid = threadIdx.x;
    int vBase = blockIdx.x * 32;

    // compute-phase lane roles
    int lane = tid & 63;
    int wv = tid >> 6;
    int vi = lane & 7;
    int tg = lane >> 3;              // 0..7
    int vLocal = wv * 8 + vi;        // 0..31
    int v = vBase + vLocal;
    bool valid = v < N;

    // gather-phase lane roles
    int d = tid & 31;
    int q = tid >> 5;                // 0..7

    float acc[8][4];
    #pragma unroll
    for (int k = 0; k < 8; ++k)
        #pragma unroll
        for (int j = 0; j < 4; ++j) acc[k][j] = 0.f;

    const float4* Wg4 = (const float4*)Wg;

    for (int r = 0; r < RR; ++r) {
        __syncthreads();  // previous iteration done with LDS

        // ---- stage W[:, r, :, :] -> LDS (coalesced float4 reads) ----
        for (int i2 = tid; i2 < 2048; i2 += 256) {
            int t = i2 >> 6;          // 0..31
            int a = (i2 >> 3) & 7;    // 0..7
            int dc = i2 & 7;          // 0..7 (d/4)
            float4 val = Wg4[((t * 5 + r) * 8 + a) * 8 + dc];
            *(float4*)&Wl[((a * 8 + dc) * 33 + t) * 4] = val;
        }

        // ---- gather + barycentric interp -> LDS tile for this r ----
        #pragma unroll
        for (int vv0 = 0; vv0 < 4; ++vv0) {
            int vv = q + vv0 * 8;            // 0..31
            int vg = vBase + vv;
            int vgc = (vg < N) ? vg : (N - 1);
            int base = (vgc * 40 + r * 8) * 3;
            #pragma unroll
            for (int a = 0; a < 8; ++a) {
                int i0 = bc_idx[base + a * 3 + 0];
                int i1 = bc_idx[base + a * 3 + 1];
                int i2 = bc_idx[base + a * 3 + 2];
                float w0 = bc_w[base + a * 3 + 0];
                float w1 = bc_w[base + a * 3 + 1];
                float w2 = bc_w[base + a * 3 + 2];
                float val = w0 * sig[(size_t)i0 * 32 + d]
                          + w1 * sig[(size_t)i1 * 32 + d]
                          + w2 * sig[(size_t)i2 * 32 + d];
                Il[vv * 260 + a * 32 + d] = val;
            }
        }
        __syncthreads();

        // ---- conv accumulate for this r ----
        const float* ipr = &Il[vLocal * 260];
        #pragma unroll 1
        for (int d0 = 0; d0 < 32; d0 += 4) {
            float4 irow[8];
            #pragma unroll
            for (int a = 0; a < 8; ++a)
                irow[a] = *(const float4*)&ipr[a * 32 + d0];
            int dc = d0 >> 2;
            #pragma unroll
            for (int ap = 0; ap < 8; ++ap) {
                float4 bf[4];
                #pragma unroll
                for (int j = 0; j < 4; ++j)
                    bf[j] = *(const float4*)&Wl[((ap * 8 + dc) * 33 + (tg + 8 * j)) * 4];
                #pragma unroll
                for (int kk = 0; kk < 8; ++kk) {
                    float4 af = irow[(ap + kk) & 7];
                    #pragma unroll
                    for (int j = 0; j < 4; ++j) {
                        acc[kk][j] = fmaf(af.x, bf[j].x, acc[kk][j]);
                        acc[kk][j] = fmaf(af.y, bf[j].y, acc[kk][j]);
                        acc[kk][j] = fmaf(af.z, bf[j].z, acc[kk][j]);
                        acc[kk][j] = fmaf(af.w, bf[j].w, acc[kk][j]);
                    }
                }
            }
        }
    }

    // bias (included in pooling norm, as in reference)
    float bj[4];
    #pragma unroll
    for (int j = 0; j < 4; ++j) bj[j] = bias[tg + 8 * j];
    #pragma unroll
    for (int k = 0; k < 8; ++k)
        #pragma unroll
        for (int j = 0; j < 4; ++j) acc[k][j] += bj[j];

    // angular max pool: argmax_k ||out[v,k,:]||_2, first-max-wins
    float best = -1.f;
    int bk = 0;
    #pragma unroll
    for (int k = 0; k < 8; ++k) {
        float nl = acc[k][0] * acc[k][0] + acc[k][1] * acc[k][1]
                 + acc[k][2] * acc[k][2] + acc[k][3] * acc[k][3];
        nl += __shfl_xor(nl, 8);
        nl += __shfl_xor(nl, 16);
        nl += __shfl_xor(nl, 32);   // sum over the 8 tg groups (full 32 t's)
        float n = sqrtf(nl);
        if (n > best) { best = n; bk = k; }
    }

    if (valid) {
        float sel0 = 0.f, sel1 = 0.f, sel2 = 0.f, sel3 = 0.f;
        #pragma unroll
        for (int k = 0; k < 8; ++k) {
            if (k == bk) { sel0 = acc[k][0]; sel1 = acc[k][1]; sel2 = acc[k][2]; sel3 = acc[k][3]; }
        }
        float* o = s_out + (size_t)v * 32 + tg;
        o[0]  = sel0;
        o[8]  = sel1;
        o[16] = sel2;
        o[24] = sel3;
    }
}

// ---------------------------------------------------------------------------
// Stats: per-column (t) sum and sumsq over N rows, fp64 accumulation.
// ---------------------------------------------------------------------------
__global__ void stats_kernel(const float* __restrict__ s,
                             double* __restrict__ sums,
                             double* __restrict__ sumsq, int n) {
    __shared__ double la[256];
    __shared__ double lb[256];
    int tid = threadIdx.x;
    int t = tid & 31;
    int row = tid >> 5;  // 0..7
    double a = 0.0, b = 0.0;
    for (int v = blockIdx.x * 8 + row; v < n; v += gridDim.x * 8) {
        float x = s[(size_t)v * 32 + t];
        a += (double)x;
        b += (double)x * (double)x;
    }
    la[tid] = a; lb[tid] = b;
    __syncthreads();
    for (int off = 128; off >= 32; off >>= 1) {
        if (tid < off) { la[tid] += la[tid + off]; lb[tid] += lb[tid + off]; }
        __syncthreads();
    }
    if (tid < 32) {
        atomicAdd(&sums[t], la[tid]);
        atomicAdd(&sumsq[t], lb[tid]);
    }
}

// ---------------------------------------------------------------------------
// Finalize BN: scale = gamma * rsqrt(var + eps), shift = beta - mu*scale
// ---------------------------------------------------------------------------
__global__ void finalize_kernel(const double* __restrict__ sums,
                                const double* __restrict__ sumsq,
                                const float* __restrict__ gamma,
                                const float* __restrict__ beta,
                                float* __restrict__ scale,
                                float* __restrict__ shift, int n) {
    int t = threadIdx.x;
    if (t < 32) {
        double mu = sums[t] / (double)n;
        double var = sumsq[t] / (double)n - mu * mu;
        double sc = (double)gamma[t] / sqrt(var + 1e-3);
        scale[t] = (float)sc;
        shift[t] = (float)((double)beta[t] - mu * sc);
    }
}

// ---------------------------------------------------------------------------
// sig2 = relu(scale*s + shift)   (branch 1 epilogue -> conv2 input)
// ---------------------------------------------------------------------------
__global__ void affine_relu_kernel(const float* __restrict__ s,
                                   const float* __restrict__ scale,
                                   const float* __restrict__ shift,
                                   float* __restrict__ o, int n4) {
    int e = blockIdx.x * blockDim.x + threadIdx.x;
    if (e >= n4) return;
    int t0 = (e & 7) * 4;
    float4 x = ((const float4*)s)[e];
    float4 y;
    y.x = fmaxf(fmaf(scale[t0 + 0], x.x, shift[t0 + 0]), 0.f);
    y.y = fmaxf(fmaf(scale[t0 + 1], x.y, shift[t0 + 1]), 0.f);
    y.z = fmaxf(fmaf(scale[t0 + 2], x.z, shift[t0 + 2]), 0.f);
    y.w = fmaxf(fmaf(scale[t0 + 3], x.w, shift[t0 + 3]), 0.f);
    ((float4*)o)[e] = y;
}

// ---------------------------------------------------------------------------
// out = relu(scale*s + shift + signal)   (final residual epilogue)
// ---------------------------------------------------------------------------
__global__ void final_kernel(const float* __restrict__ s,
                             const float* __restrict__ scale,
                             const float* __restrict__ shift,
                             const float* __restrict__ sig,
                             float* __restrict__ o, int n4) {
    int e = blockIdx.x * blockDim.x + threadIdx.x;
    if (e >= n4) return;
    int t0 = (e & 7) * 4;
    float4 x = ((const float4*)s)[e];
    float4 z = ((const float4*)sig)[e];
    float4 y;
    y.x = fmaxf(fmaf(scale[t0 + 0], x.x, shift[t0 + 0]) + z.x, 0.f);
    y.y = fmaxf(fmaf(scale[t0 + 1], x.y, shift[t0 + 1]) + z.y, 0.f);
    y.z = fmaxf(fmaf(scale[t0 + 2], x.z, shift[t0 + 2]) + z.z, 0.f);
    y.w = fmaxf(fmaf(scale[t0 + 3], x.w, shift[t0 + 3]) + z.w, 0.f);
    ((float4*)o)[e] = y;
}

__global__ void zero_stats_kernel(double* __restrict__ d, float* __restrict__ f) {
    int t = threadIdx.x;
    if (t < 128) d[t] = 0.0;
    if (t < 128) f[t] = 0.f;
}

// ---------------------------------------------------------------------------
extern "C" void kernel_launch(void* const* d_in, const int* in_sizes, int n_in,
                              void* d_out, int out_size, void* d_ws, size_t ws_size,
                              hipStream_t stream) {
    const float* signal = (const float*)d_in[0];
    const int* bc_idx   = (const int*)d_in[1];
    const float* bc_w   = (const float*)d_in[2];
    const float* W1     = (const float*)d_in[3];
    const float* b1     = (const float*)d_in[4];
    const float* g1     = (const float*)d_in[5];
    const float* be1    = (const float*)d_in[6];
    const float* W2     = (const float*)d_in[7];
    const float* b2     = (const float*)d_in[8];
    const float* g2     = (const float*)d_in[9];
    const float* be2    = (const float*)d_in[10];
    float* out = (float*)d_out;

    const int N = in_sizes[0] / 32;  // 80000

    char* ws = (char*)d_ws;
    double* sums1  = (double*)ws;         // 32
    double* sumsq1 = sums1 + 32;
    double* sums2  = sums1 + 64;
    double* sumsq2 = sums1 + 96;
    float* scale1 = (float*)(ws + 1024);
    float* shift1 = scale1 + 32;
    float* scale2 = scale1 + 64;
    float* shift2 = scale1 + 96;
    float* s1  = (float*)(ws + 4096);
    float* sg2 = s1 + (size_t)N * 32;
    float* s2  = sg2 + (size_t)N * 32;

    int nBlocks = (N + 31) / 32;

    zero_stats_kernel<<<1, 128, 0, stream>>>((double*)ws, (float*)(ws + 1024));

    // ---- branch 1: fused gather+conv+pool ----
    fused_conv_kernel<<<nBlocks, 256, 0, stream>>>(signal, bc_idx, bc_w, W1, b1, s1, N);
    stats_kernel<<<64, 256, 0, stream>>>(s1, sums1, sumsq1, N);
    finalize_kernel<<<1, 32, 0, stream>>>(sums1, sumsq1, g1, be1, scale1, shift1, N);
    affine_relu_kernel<<<(N * 8 + 255) / 256, 256, 0, stream>>>(s1, scale1, shift1, sg2, N * 8);

    // ---- branch 2 ----
    fused_conv_kernel<<<nBlocks, 256, 0, stream>>>(sg2, bc_idx, bc_w, W2, b2, s2, N);
    stats_kernel<<<64, 256, 0, stream>>>(s2, sums2, sumsq2, N);
    finalize_kernel<<<1, 32, 0, stream>>>(sums2, sumsq2, g2, be2, scale2, shift2, N);

    // ---- residual + relu ----
    final_kernel<<<(N * 8 + 255) / 256, 256, 0, stream>>>(s2, scale2, shift2, signal, out, N * 8);
}

// Round 3
// 1316.742 us; speedup vs baseline: 2.7453x; 1.0976x over previous
//
#include <hip/hip_runtime.h>
#include <math.h>

// Problem constants (N=80000, Rr=5, A=8, D=32, T=32, K=8 rotations, ROT_DELTA=1)
#define RR 5
#define AA 8
#define DD 32
#define TT 32
#define KK 8
#define MM 1280  // RR*AA*DD

typedef float v2f __attribute__((ext_vector_type(2)));
typedef float v4f __attribute__((ext_vector_type(4)));

static __device__ __forceinline__ v2f pkfma(v2f a, v2f b, v2f c) {
#if __has_builtin(__builtin_elementwise_fma)
    return __builtin_elementwise_fma(a, b, c);
#else
    v2f r; r.x = fmaf(a.x, b.x, c.x); r.y = fmaf(a.y, b.y, c.y); return r;
#endif
}

// ---------------------------------------------------------------------------
// Fused kernel: barycentric interp (gather) + conv + bias + angular max pool.
// out[v,k,t] = sum_{r,a',d} interp[v,r,(a'+k)&7,d] * W[t,r,a',d] + b[t]
//   interp[v,r,a,d] = sum_i bc_w[v,r,a,i] * sig[bc_idx[v,r,a,i], d]
//
// Block = 256 threads (4 waves), 32 vertices/block.
// Per r-chunk: stage W[:,r,:,:] (32 KB) and interp tile (32 KB) in LDS.
//   Gather phase lanes: d2 = tid&15 (float2, coalesced dwordx2 sig rows),
//   g = tid>>4 (16 vertex groups, 2 passes for 32 v).
//   Compute phase lanes: vi = lane&7 (vertex), tg = lane>>3; per-lane tile
//   8 k x 4 t (t = tg+8j), accumulators are v2f (two d-interleaved partial
//   sums -> v_pk_fma_f32), horizontal add at epilogue.
//   Il stride 260 => b128 reads at bank-quad 4*vi: conflict-free.
//   Wl stride 33 (t) => bank-quad 4*tg: conflict-free.
// ---------------------------------------------------------------------------
__global__ __launch_bounds__(256, 2)
void fused_conv_kernel(const float* __restrict__ sig,
                       const int* __restrict__ bc_idx,
                       const float* __restrict__ bc_w,
                       const float* __restrict__ Wg,
                       const float* __restrict__ bias,
                       float* __restrict__ s_out,
                       int N) {
    __shared__ float Wl[8448];      // ~33.8 KB
    __shared__ float Il[32 * 260];  // ~33.3 KB

    int tid = threadIdx.x;
    int vBase = blockIdx.x * 32;

    // compute-phase lane roles
    int lane = tid & 63;
    int wv = tid >> 6;
    int vi = lane & 7;
    int tg = lane >> 3;              // 0..7
    int vLocal = wv * 8 + vi;        // 0..31
    int v = vBase + vLocal;
    bool valid = v < N;

    // gather-phase lane roles (float2 granularity)
    int d2 = tid & 15;               // float2 index: floats 2*d2, 2*d2+1
    int g = tid >> 4;                // 0..15

    v2f acc2[8][4];
    #pragma unroll
    for (int k = 0; k < 8; ++k)
        #pragma unroll
        for (int j = 0; j < 4; ++j) acc2[k][j] = (v2f){0.f, 0.f};

    const float4* Wg4 = (const float4*)Wg;

    for (int r = 0; r < RR; ++r) {
        __syncthreads();  // previous iteration done with LDS

        // ---- stage W[:, r, :, :] -> LDS (coalesced float4 reads) ----
        for (int i2 = tid; i2 < 2048; i2 += 256) {
            int t = i2 >> 6;          // 0..31
            int a = (i2 >> 3) & 7;    // 0..7
            int dc = i2 & 7;          // 0..7 (d/4)
            float4 val = Wg4[((t * 5 + r) * 8 + a) * 8 + dc];
            *(float4*)&Wl[((a * 8 + dc) * 33 + t) * 4] = val;
        }

        // ---- gather + barycentric interp -> LDS tile for this r ----
        #pragma unroll
        for (int vv0 = 0; vv0 < 2; ++vv0) {
            int vv = g + vv0 * 16;           // 0..31
            int vg = vBase + vv;
            int vgc = (vg < N) ? vg : (N - 1);
            int base = (vgc * 40 + r * 8) * 3;
            #pragma unroll
            for (int a = 0; a < 8; ++a) {
                int i0 = bc_idx[base + a * 3 + 0];
                int i1 = bc_idx[base + a * 3 + 1];
                int i2 = bc_idx[base + a * 3 + 2];
                float w0 = bc_w[base + a * 3 + 0];
                float w1 = bc_w[base + a * 3 + 1];
                float w2 = bc_w[base + a * 3 + 2];
                v2f r0 = *(const v2f*)&sig[(size_t)i0 * 32 + 2 * d2];
                v2f r1 = *(const v2f*)&sig[(size_t)i1 * 32 + 2 * d2];
                v2f r2 = *(const v2f*)&sig[(size_t)i2 * 32 + 2 * d2];
                v2f w0v = {w0, w0};
                v2f w1v = {w1, w1};
                v2f w2v = {w2, w2};
                v2f val = pkfma(w2v, r2, pkfma(w1v, r1, w0v * r0));
                *(v2f*)&Il[vv * 260 + a * 32 + 2 * d2] = val;
            }
        }
        __syncthreads();

        // ---- conv accumulate for this r (packed fp32) ----
        const float* ipr = &Il[vLocal * 260];
        #pragma unroll 1
        for (int d0 = 0; d0 < 32; d0 += 4) {
            v4f irow[8];
            #pragma unroll
            for (int a = 0; a < 8; ++a)
                irow[a] = *(const v4f*)&ipr[a * 32 + d0];
            int dc = d0 >> 2;
            #pragma unroll
            for (int ap = 0; ap < 8; ++ap) {
                v4f bf[4];
                #pragma unroll
                for (int j = 0; j < 4; ++j)
                    bf[j] = *(const v4f*)&Wl[((ap * 8 + dc) * 33 + (tg + 8 * j)) * 4];
                #pragma unroll
                for (int kk = 0; kk < 8; ++kk) {
                    v4f af = irow[(ap + kk) & 7];
                    #pragma unroll
                    for (int j = 0; j < 4; ++j) {
                        acc2[kk][j] = pkfma(af.xy, bf[j].xy, acc2[kk][j]);
                        acc2[kk][j] = pkfma(af.zw, bf[j].zw, acc2[kk][j]);
                    }
                }
            }
        }
    }

    // horizontal add + bias (included in pooling norm, as in reference)
    float accs[8][4];
    float bj[4];
    #pragma unroll
    for (int j = 0; j < 4; ++j) bj[j] = bias[tg + 8 * j];
    #pragma unroll
    for (int k = 0; k < 8; ++k)
        #pragma unroll
        for (int j = 0; j < 4; ++j)
            accs[k][j] = acc2[k][j].x + acc2[k][j].y + bj[j];

    // angular max pool: argmax_k ||out[v,k,:]||_2, first-max-wins
    float best = -1.f;
    int bk = 0;
    #pragma unroll
    for (int k = 0; k < 8; ++k) {
        float nl = accs[k][0] * accs[k][0] + accs[k][1] * accs[k][1]
                 + accs[k][2] * accs[k][2] + accs[k][3] * accs[k][3];
        nl += __shfl_xor(nl, 8);
        nl += __shfl_xor(nl, 16);
        nl += __shfl_xor(nl, 32);   // sum over the 8 tg groups (full 32 t's)
        float n = sqrtf(nl);
        if (n > best) { best = n; bk = k; }
    }

    if (valid) {
        float sel0 = 0.f, sel1 = 0.f, sel2 = 0.f, sel3 = 0.f;
        #pragma unroll
        for (int k = 0; k < 8; ++k) {
            if (k == bk) { sel0 = accs[k][0]; sel1 = accs[k][1]; sel2 = accs[k][2]; sel3 = accs[k][3]; }
        }
        float* o = s_out + (size_t)v * 32 + tg;
        o[0]  = sel0;
        o[8]  = sel1;
        o[16] = sel2;
        o[24] = sel3;
    }
}

// ---------------------------------------------------------------------------
// Stats: per-column (t) sum and sumsq over N rows, fp64 accumulation.
// ---------------------------------------------------------------------------
__global__ void stats_kernel(const float* __restrict__ s,
                             double* __restrict__ sums,
                             double* __restrict__ sumsq, int n) {
    __shared__ double la[256];
    __shared__ double lb[256];
    int tid = threadIdx.x;
    int t = tid & 31;
    int row = tid >> 5;  // 0..7
    double a = 0.0, b = 0.0;
    for (int v = blockIdx.x * 8 + row; v < n; v += gridDim.x * 8) {
        float x = s[(size_t)v * 32 + t];
        a += (double)x;
        b += (double)x * (double)x;
    }
    la[tid] = a; lb[tid] = b;
    __syncthreads();
    for (int off = 128; off >= 32; off >>= 1) {
        if (tid < off) { la[tid] += la[tid + off]; lb[tid] += lb[tid + off]; }
        __syncthreads();
    }
    if (tid < 32) {
        atomicAdd(&sums[t], la[tid]);
        atomicAdd(&sumsq[t], lb[tid]);
    }
}

// ---------------------------------------------------------------------------
// Finalize BN: scale = gamma * rsqrt(var + eps), shift = beta - mu*scale
// ---------------------------------------------------------------------------
__global__ void finalize_kernel(const double* __restrict__ sums,
                                const double* __restrict__ sumsq,
                                const float* __restrict__ gamma,
                                const float* __restrict__ beta,
                                float* __restrict__ scale,
                                float* __restrict__ shift, int n) {
    int t = threadIdx.x;
    if (t < 32) {
        double mu = sums[t] / (double)n;
        double var = sumsq[t] / (double)n - mu * mu;
        double sc = (double)gamma[t] / sqrt(var + 1e-3);
        scale[t] = (float)sc;
        shift[t] = (float)((double)beta[t] - mu * sc);
    }
}

// ---------------------------------------------------------------------------
// sig2 = relu(scale*s + shift)   (branch 1 epilogue -> conv2 input)
// ---------------------------------------------------------------------------
__global__ void affine_relu_kernel(const float* __restrict__ s,
                                   const float* __restrict__ scale,
                                   const float* __restrict__ shift,
                                   float* __restrict__ o, int n4) {
    int e = blockIdx.x * blockDim.x + threadIdx.x;
    if (e >= n4) return;
    int t0 = (e & 7) * 4;
    float4 x = ((const float4*)s)[e];
    float4 y;
    y.x = fmaxf(fmaf(scale[t0 + 0], x.x, shift[t0 + 0]), 0.f);
    y.y = fmaxf(fmaf(scale[t0 + 1], x.y, shift[t0 + 1]), 0.f);
    y.z = fmaxf(fmaf(scale[t0 + 2], x.z, shift[t0 + 2]), 0.f);
    y.w = fmaxf(fmaf(scale[t0 + 3], x.w, shift[t0 + 3]), 0.f);
    ((float4*)o)[e] = y;
}

// ---------------------------------------------------------------------------
// out = relu(scale*s + shift + signal)   (final residual epilogue)
// ---------------------------------------------------------------------------
__global__ void final_kernel(const float* __restrict__ s,
                             const float* __restrict__ scale,
                             const float* __restrict__ shift,
                             const float* __restrict__ sig,
                             float* __restrict__ o, int n4) {
    int e = blockIdx.x * blockDim.x + threadIdx.x;
    if (e >= n4) return;
    int t0 = (e & 7) * 4;
    float4 x = ((const float4*)s)[e];
    float4 z = ((const float4*)sig)[e];
    float4 y;
    y.x = fmaxf(fmaf(scale[t0 + 0], x.x, shift[t0 + 0]) + z.x, 0.f);
    y.y = fmaxf(fmaf(scale[t0 + 1], x.y, shift[t0 + 1]) + z.y, 0.f);
    y.z = fmaxf(fmaf(scale[t0 + 2], x.z, shift[t0 + 2]) + z.z, 0.f);
    y.w = fmaxf(fmaf(scale[t0 + 3], x.w, shift[t0 + 3]) + z.w, 0.f);
    ((float4*)o)[e] = y;
}

__global__ void zero_stats_kernel(double* __restrict__ d, float* __restrict__ f) {
    int t = threadIdx.x;
    if (t < 128) d[t] = 0.0;
    if (t < 128) f[t] = 0.f;
}

// ---------------------------------------------------------------------------
extern "C" void kernel_launch(void* const* d_in, const int* in_sizes, int n_in,
                              void* d_out, int out_size, void* d_ws, size_t ws_size,
                              hipStream_t stream) {
    const float* signal = (const float*)d_in[0];
    const int* bc_idx   = (const int*)d_in[1];
    const float* bc_w   = (const float*)d_in[2];
    const float* W1     = (const float*)d_in[3];
    const float* b1     = (const float*)d_in[4];
    const float* g1     = (const float*)d_in[5];
    const float* be1    = (const float*)d_in[6];
    const float* W2     = (const float*)d_in[7];
    const float* b2     = (const float*)d_in[8];
    const float* g2     = (const float*)d_in[9];
    const float* be2    = (const float*)d_in[10];
    float* out = (float*)d_out;

    const int N = in_sizes[0] / 32;  // 80000

    char* ws = (char*)d_ws;
    double* sums1  = (double*)ws;         // 32
    double* sumsq1 = sums1 + 32;
    double* sums2  = sums1 + 64;
    double* sumsq2 = sums1 + 96;
    float* scale1 = (float*)(ws + 1024);
    float* shift1 = scale1 + 32;
    float* scale2 = scale1 + 64;
    float* shift2 = scale1 + 96;
    float* s1  = (float*)(ws + 4096);
    float* sg2 = s1 + (size_t)N * 32;
    float* s2  = sg2 + (size_t)N * 32;

    int nBlocks = (N + 31) / 32;

    zero_stats_kernel<<<1, 128, 0, stream>>>((double*)ws, (float*)(ws + 1024));

    // ---- branch 1: fused gather+conv+pool ----
    fused_conv_kernel<<<nBlocks, 256, 0, stream>>>(signal, bc_idx, bc_w, W1, b1, s1, N);
    stats_kernel<<<64, 256, 0, stream>>>(s1, sums1, sumsq1, N);
    finalize_kernel<<<1, 32, 0, stream>>>(sums1, sumsq1, g1, be1, scale1, shift1, N);
    affine_relu_kernel<<<(N * 8 + 255) / 256, 256, 0, stream>>>(s1, scale1, shift1, sg2, N * 8);

    // ---- branch 2 ----
    fused_conv_kernel<<<nBlocks, 256, 0, stream>>>(sg2, bc_idx, bc_w, W2, b2, s2, N);
    stats_kernel<<<64, 256, 0, stream>>>(s2, sums2, sumsq2, N);
    finalize_kernel<<<1, 32, 0, stream>>>(sums2, sumsq2, g2, be2, scale2, shift2, N);

    // ---- residual + relu ----
    final_kernel<<<(N * 8 + 255) / 256, 256, 0, stream>>>(s2, scale2, shift2, signal, out, N * 8);
}

// Round 4
// 748.506 us; speedup vs baseline: 4.8294x; 1.7592x over previous
//
#include <hip/hip_runtime.h>
#include <math.h>

// Problem constants (N=80000, Rr=5, A=8, D=32, T=32, K=8 rotations, ROT_DELTA=1)
#define RR 5
#define AA 8
#define DD 32
#define TT 32
#define KK 8
#define MM 1280  // RR*AA*DD

#define RT2 0.70710678118654752f

typedef float v2f __attribute__((ext_vector_type(2)));
typedef float v4f __attribute__((ext_vector_type(4)));

static __device__ __forceinline__ v2f pkfma(v2f a, v2f b, v2f c) {
#if __has_builtin(__builtin_elementwise_fma)
    return __builtin_elementwise_fma(a, b, c);
#else
    v2f r; r.x = fmaf(a.x, b.x, c.x); r.y = fmaf(a.y, b.y, c.y); return r;
#endif
}

// ---------------------------------------------------------------------------
// W spectral precompute: Ws[t*5+r][d*8+f] = DFT8_a(W[t,r,a,d]) packed as
// [F0, F4, Re1, Im1, Re2, Im2, Re3, Im3].  One thread per (t,r,d) = 5120.
// ---------------------------------------------------------------------------
__global__ void wdft_kernel(const float* __restrict__ W, float* __restrict__ Ws) {
    int idx = blockIdx.x * 256 + threadIdx.x;
    if (idx >= TT * RR * DD) return;
    int d = idx & 31;
    int tr = idx >> 5;  // t*5+r
    float xa[8];
    #pragma unroll
    for (int a = 0; a < 8; ++a) xa[a] = W[(tr * 8 + a) * 32 + d];
    float s0 = xa[0] + xa[4], d0 = xa[0] - xa[4];
    float s1 = xa[1] + xa[5], d1 = xa[1] - xa[5];
    float s2 = xa[2] + xa[6], d2 = xa[2] - xa[6];
    float s3 = xa[3] + xa[7], d3 = xa[3] - xa[7];
    float s02 = s0 + s2, s13 = s1 + s3;
    float F0 = s02 + s13, F4 = s02 - s13;
    float R2 = s0 - s2, I2 = s3 - s1;
    float u = RT2 * (d1 - d3), v = RT2 * (d1 + d3);
    float R1 = d0 + u, R3 = d0 - u;
    float I1 = -d2 - v, I3 = d2 - v;
    float* o = &Ws[tr * 256 + d * 8];
    o[0] = F0; o[1] = F4; o[2] = R1; o[3] = I1;
    o[4] = R2; o[5] = I2; o[6] = R3; o[7] = I3;
}

// ---------------------------------------------------------------------------
// Fused kernel: gather + barycentric interp + forward DFT8 + spectral GEMM
// (vs conj(W-spectrum)) + IDFT8 + bias + angular max pool.
//
// out[v,k,t] = sum_a interp[v,a]·W[t,(a-k)&7]  (per rd, summed)
//            = IDFT_k( sum_rd Î[f]·conj(Ŵ[f]) )
//
// Block = 256 threads (4 waves), 32 vertices/block, 2 blocks/CU.
// Per r: stage Ŵ[:,r] slice (33 KB) in LDS; gather lanes (d2=tid&15 float2,
// g=tid>>4 vertex) compute interp, DFT8 in-register, transpose-write spectra
// to Is[v][d][f] (stride 260: 2-way-max conflicts on b128 writes, free).
// Compute lanes (vi=lane&7 vertex, tg=lane>>3): per d read Is[v][d][0..8)
// (2 b128, 8-way tg-broadcast) and Ŵ[t][d][0..8) for 4 t's (8 b128, 8-way
// vi-broadcast), 7 pk_fma per (t,d) into 4 v2f spectral accumulators per t.
// Epilogue: IDFT8 per t (+bias), then norm/argmax/store as before.
// ---------------------------------------------------------------------------
__global__ __launch_bounds__(256, 2)
void fused_conv_kernel(const float* __restrict__ sig,
                       const int* __restrict__ bc_idx,
                       const float* __restrict__ bc_w,
                       const float* __restrict__ Wsg,
                       const float* __restrict__ bias,
                       float* __restrict__ s_out,
                       int N) {
    __shared__ float Wl[32 * 260];  // ~33.3 KB spectral W slice
    __shared__ float Is[32 * 260];  // ~33.3 KB spectral interp

    int tid = threadIdx.x;
    int vBase = blockIdx.x * 32;

    // compute-phase lane roles
    int lane = tid & 63;
    int wv = tid >> 6;
    int vi = lane & 7;
    int tg = lane >> 3;              // 0..7
    int vLocal = wv * 8 + vi;        // 0..31
    int v = vBase + vLocal;
    bool valid = v < N;

    // gather-phase lane roles (float2 granularity)
    int d2 = tid & 15;               // float2 index: floats 2*d2, 2*d2+1
    int g = tid >> 4;                // 0..15

    // spectral accumulators: per j (t=tg+8j): A0=(C0,C4) A1=(R1,I1) A2 A3
    v2f A0[4], A1[4], A2[4], A3[4];
    #pragma unroll
    for (int j = 0; j < 4; ++j) {
        A0[j] = (v2f){0.f, 0.f}; A1[j] = (v2f){0.f, 0.f};
        A2[j] = (v2f){0.f, 0.f}; A3[j] = (v2f){0.f, 0.f};
    }

    const float4* Ws4 = (const float4*)Wsg;
    const v2f rt2 = {RT2, RT2};

    for (int r = 0; r < RR; ++r) {
        __syncthreads();  // previous iteration done with LDS

        // ---- stage Ŵ[:, r] slice -> LDS (coalesced float4) ----
        for (int i2 = tid; i2 < 2048; i2 += 256) {
            int t = i2 >> 6;          // 0..31
            int u4 = i2 & 63;         // float4 unit within 256-float row
            float4 val = Ws4[(t * 5 + r) * 64 + u4];
            *(float4*)&Wl[t * 260 + u4 * 4] = val;
        }

        // ---- gather + interp + forward DFT8 -> Is ----
        #pragma unroll
        for (int vv0 = 0; vv0 < 2; ++vv0) {
            int vv = g + vv0 * 16;           // 0..31
            int vg = vBase + vv;
            int vgc = (vg < N) ? vg : (N - 1);
            int base = (vgc * 40 + r * 8) * 3;
            v2f xa[8];
            #pragma unroll
            for (int a = 0; a < 8; ++a) {
                int i0 = bc_idx[base + a * 3 + 0];
                int i1 = bc_idx[base + a * 3 + 1];
                int i2 = bc_idx[base + a * 3 + 2];
                float w0 = bc_w[base + a * 3 + 0];
                float w1 = bc_w[base + a * 3 + 1];
                float w2 = bc_w[base + a * 3 + 2];
                v2f r0 = *(const v2f*)&sig[(size_t)i0 * 32 + 2 * d2];
                v2f r1 = *(const v2f*)&sig[(size_t)i1 * 32 + 2 * d2];
                v2f r2 = *(const v2f*)&sig[(size_t)i2 * 32 + 2 * d2];
                v2f w0v = {w0, w0};
                v2f w1v = {w1, w1};
                v2f w2v = {w2, w2};
                xa[a] = pkfma(w2v, r2, pkfma(w1v, r1, w0v * r0));
            }
            // DFT8 (2 d-channels packed)
            v2f s0 = xa[0] + xa[4], dd0 = xa[0] - xa[4];
            v2f s1 = xa[1] + xa[5], dd1 = xa[1] - xa[5];
            v2f s2 = xa[2] + xa[6], dd2 = xa[2] - xa[6];
            v2f s3 = xa[3] + xa[7], dd3 = xa[3] - xa[7];
            v2f s02 = s0 + s2, s13 = s1 + s3;
            v2f F0 = s02 + s13, F4 = s02 - s13;
            v2f R2 = s0 - s2, I2 = s3 - s1;
            v2f u = rt2 * (dd1 - dd3), vv_ = rt2 * (dd1 + dd3);
            v2f R1 = dd0 + u, R3 = dd0 - u;
            v2f I1 = -dd2 - vv_, I3 = dd2 - vv_;
            // transpose to per-d spectra and write (4 x b128)
            float* ob = &Is[vv * 260 + (2 * d2) * 8];
            v4f lo0 = {F0.x, F4.x, R1.x, I1.x};
            v4f lo1 = {R2.x, I2.x, R3.x, I3.x};
            v4f hi0 = {F0.y, F4.y, R1.y, I1.y};
            v4f hi1 = {R2.y, I2.y, R3.y, I3.y};
            *(v4f*)&ob[0] = lo0;
            *(v4f*)&ob[4] = lo1;
            *(v4f*)&ob[8] = hi0;
            *(v4f*)&ob[12] = hi1;
        }
        __syncthreads();

        // ---- spectral GEMM for this r ----
        const float* ip = &Is[vLocal * 260];
        const float* wp = &Wl[tg * 260];  // t = tg+8j -> +8j*260
        #pragma unroll 4
        for (int d = 0; d < 32; ++d) {
            v4f p0 = *(const v4f*)&ip[d * 8];
            v4f p1 = *(const v4f*)&ip[d * 8 + 4];
            v2f x04 = p0.xy;            // (F0, F4)
            v2f x1 = p0.zw;             // (Re1, Im1)
            v2f x2 = p1.xy;
            v2f x3 = p1.zw;
            v2f x1n = {x1.y, -x1.x};    // (Im, -Re) for conj(H) cross term
            v2f x2n = {x2.y, -x2.x};
            v2f x3n = {x3.y, -x3.x};
            #pragma unroll
            for (int j = 0; j < 4; ++j) {
                v4f q0 = *(const v4f*)&wp[j * 8 * 260 + d * 8];
                v4f q1 = *(const v4f*)&wp[j * 8 * 260 + d * 8 + 4];
                A0[j] = pkfma(x04, q0.xy, A0[j]);
                A1[j] = pkfma(x1, (v2f){q0.z, q0.z}, A1[j]);
                A1[j] = pkfma(x1n, (v2f){q0.w, q0.w}, A1[j]);
                A2[j] = pkfma(x2, (v2f){q1.x, q1.x}, A2[j]);
                A2[j] = pkfma(x2n, (v2f){q1.y, q1.y}, A2[j]);
                A3[j] = pkfma(x3, (v2f){q1.z, q1.z}, A3[j]);
                A3[j] = pkfma(x3n, (v2f){q1.w, q1.w}, A3[j]);
            }
        }
    }

    // ---- IDFT8 + bias per t ----
    float outk[8][4];
    #pragma unroll
    for (int j = 0; j < 4; ++j) {
        float C0 = A0[j].x, C4 = A0[j].y;
        float R1 = A1[j].x, I1 = A1[j].y;
        float R2 = A2[j].x, I2 = A2[j].y;
        float R3 = A3[j].x, I3 = A3[j].y;
        float e = 0.125f * (C0 + C4), o = 0.125f * (C0 - C4);
        float p = 0.25f * (R1 + R3), q = 0.25f * R2, s = 0.25f * (I1 - I3);
        float a_ = 0.25f * RT2 * (R1 - R3);
        float b_ = 0.25f * RT2 * (I1 + I3);
        float c_ = 0.25f * I2;
        float bb = bias[tg + 8 * j];
        outk[0][j] = e + p + q + bb;
        outk[1][j] = o + a_ - b_ - c_ + bb;
        outk[2][j] = e - s - q + bb;
        outk[3][j] = o - a_ - b_ + c_ + bb;
        outk[4][j] = e - p + q + bb;
        outk[5][j] = o - a_ + b_ - c_ + bb;
        outk[6][j] = e + s - q + bb;
        outk[7][j] = o + a_ + b_ + c_ + bb;
    }

    // angular max pool: argmax_k ||out[v,k,:]||_2, first-max-wins
    float best = -1.f;
    int bk = 0;
    #pragma unroll
    for (int k = 0; k < 8; ++k) {
        float nl = outk[k][0] * outk[k][0] + outk[k][1] * outk[k][1]
                 + outk[k][2] * outk[k][2] + outk[k][3] * outk[k][3];
        nl += __shfl_xor(nl, 8);
        nl += __shfl_xor(nl, 16);
        nl += __shfl_xor(nl, 32);   // sum over the 8 tg groups (full 32 t's)
        float n = sqrtf(nl);
        if (n > best) { best = n; bk = k; }
    }

    if (valid) {
        float sel0 = 0.f, sel1 = 0.f, sel2 = 0.f, sel3 = 0.f;
        #pragma unroll
        for (int k = 0; k < 8; ++k) {
            if (k == bk) { sel0 = outk[k][0]; sel1 = outk[k][1]; sel2 = outk[k][2]; sel3 = outk[k][3]; }
        }
        float* o = s_out + (size_t)v * 32 + tg;
        o[0]  = sel0;
        o[8]  = sel1;
        o[16] = sel2;
        o[24] = sel3;
    }
}

// ---------------------------------------------------------------------------
// Stats: per-column (t) sum and sumsq over N rows, fp64 accumulation.
// ---------------------------------------------------------------------------
__global__ void stats_kernel(const float* __restrict__ s,
                             double* __restrict__ sums,
                             double* __restrict__ sumsq, int n) {
    __shared__ double la[256];
    __shared__ double lb[256];
    int tid = threadIdx.x;
    int t = tid & 31;
    int row = tid >> 5;  // 0..7
    double a = 0.0, b = 0.0;
    for (int v = blockIdx.x * 8 + row; v < n; v += gridDim.x * 8) {
        float x = s[(size_t)v * 32 + t];
        a += (double)x;
        b += (double)x * (double)x;
    }
    la[tid] = a; lb[tid] = b;
    __syncthreads();
    for (int off = 128; off >= 32; off >>= 1) {
        if (tid < off) { la[tid] += la[tid + off]; lb[tid] += lb[tid + off]; }
        __syncthreads();
    }
    if (tid < 32) {
        atomicAdd(&sums[t], la[tid]);
        atomicAdd(&sumsq[t], lb[tid]);
    }
}

// ---------------------------------------------------------------------------
// Finalize BN: scale = gamma * rsqrt(var + eps), shift = beta - mu*scale
// ---------------------------------------------------------------------------
__global__ void finalize_kernel(const double* __restrict__ sums,
                                const double* __restrict__ sumsq,
                                const float* __restrict__ gamma,
                                const float* __restrict__ beta,
                                float* __restrict__ scale,
                                float* __restrict__ shift, int n) {
    int t = threadIdx.x;
    if (t < 32) {
        double mu = sums[t] / (double)n;
        double var = sumsq[t] / (double)n - mu * mu;
        double sc = (double)gamma[t] / sqrt(var + 1e-3);
        scale[t] = (float)sc;
        shift[t] = (float)((double)beta[t] - mu * sc);
    }
}

// ---------------------------------------------------------------------------
// sig2 = relu(scale*s + shift)   (branch 1 epilogue -> conv2 input)
// ---------------------------------------------------------------------------
__global__ void affine_relu_kernel(const float* __restrict__ s,
                                   const float* __restrict__ scale,
                                   const float* __restrict__ shift,
                                   float* __restrict__ o, int n4) {
    int e = blockIdx.x * blockDim.x + threadIdx.x;
    if (e >= n4) return;
    int t0 = (e & 7) * 4;
    float4 x = ((const float4*)s)[e];
    float4 y;
    y.x = fmaxf(fmaf(scale[t0 + 0], x.x, shift[t0 + 0]), 0.f);
    y.y = fmaxf(fmaf(scale[t0 + 1], x.y, shift[t0 + 1]), 0.f);
    y.z = fmaxf(fmaf(scale[t0 + 2], x.z, shift[t0 + 2]), 0.f);
    y.w = fmaxf(fmaf(scale[t0 + 3], x.w, shift[t0 + 3]), 0.f);
    ((float4*)o)[e] = y;
}

// ---------------------------------------------------------------------------
// out = relu(scale*s + shift + signal)   (final residual epilogue)
// ---------------------------------------------------------------------------
__global__ void final_kernel(const float* __restrict__ s,
                             const float* __restrict__ scale,
                             const float* __restrict__ shift,
                             const float* __restrict__ sig,
                             float* __restrict__ o, int n4) {
    int e = blockIdx.x * blockDim.x + threadIdx.x;
    if (e >= n4) return;
    int t0 = (e & 7) * 4;
    float4 x = ((const float4*)s)[e];
    float4 z = ((const float4*)sig)[e];
    float4 y;
    y.x = fmaxf(fmaf(scale[t0 + 0], x.x, shift[t0 + 0]) + z.x, 0.f);
    y.y = fmaxf(fmaf(scale[t0 + 1], x.y, shift[t0 + 1]) + z.y, 0.f);
    y.z = fmaxf(fmaf(scale[t0 + 2], x.z, shift[t0 + 2]) + z.z, 0.f);
    y.w = fmaxf(fmaf(scale[t0 + 3], x.w, shift[t0 + 3]) + z.w, 0.f);
    ((float4*)o)[e] = y;
}

__global__ void zero_stats_kernel(double* __restrict__ d, float* __restrict__ f) {
    int t = threadIdx.x;
    if (t < 128) d[t] = 0.0;
    if (t < 128) f[t] = 0.f;
}

// ---------------------------------------------------------------------------
extern "C" void kernel_launch(void* const* d_in, const int* in_sizes, int n_in,
                              void* d_out, int out_size, void* d_ws, size_t ws_size,
                              hipStream_t stream) {
    const float* signal = (const float*)d_in[0];
    const int* bc_idx   = (const int*)d_in[1];
    const float* bc_w   = (const float*)d_in[2];
    const float* W1     = (const float*)d_in[3];
    const float* b1     = (const float*)d_in[4];
    const float* g1     = (const float*)d_in[5];
    const float* be1    = (const float*)d_in[6];
    const float* W2     = (const float*)d_in[7];
    const float* b2     = (const float*)d_in[8];
    const float* g2     = (const float*)d_in[9];
    const float* be2    = (const float*)d_in[10];
    float* out = (float*)d_out;

    const int N = in_sizes[0] / 32;  // 80000

    char* ws = (char*)d_ws;
    double* sums1  = (double*)ws;         // 32
    double* sumsq1 = sums1 + 32;
    double* sums2  = sums1 + 64;
    double* sumsq2 = sums1 + 96;
    float* scale1 = (float*)(ws + 1024);
    float* shift1 = scale1 + 32;
    float* scale2 = scale1 + 64;
    float* shift2 = scale1 + 96;
    float* Ws1 = (float*)(ws + 4096);                 // 40960 floats = 160 KB
    float* Ws2 = Ws1 + TT * RR * 256;
    float* s1  = Ws2 + TT * RR * 256;
    float* sg2 = s1 + (size_t)N * 32;
    float* s2  = sg2 + (size_t)N * 32;

    int nBlocks = (N + 31) / 32;
    int wBlocks = (TT * RR * DD + 255) / 256;  // 20

    zero_stats_kernel<<<1, 128, 0, stream>>>((double*)ws, (float*)(ws + 1024));
    wdft_kernel<<<wBlocks, 256, 0, stream>>>(W1, Ws1);
    wdft_kernel<<<wBlocks, 256, 0, stream>>>(W2, Ws2);

    // ---- branch 1: fused gather+DFT+spectral-conv+pool ----
    fused_conv_kernel<<<nBlocks, 256, 0, stream>>>(signal, bc_idx, bc_w, Ws1, b1, s1, N);
    stats_kernel<<<64, 256, 0, stream>>>(s1, sums1, sumsq1, N);
    finalize_kernel<<<1, 32, 0, stream>>>(sums1, sumsq1, g1, be1, scale1, shift1, N);
    affine_relu_kernel<<<(N * 8 + 255) / 256, 256, 0, stream>>>(s1, scale1, shift1, sg2, N * 8);

    // ---- branch 2 ----
    fused_conv_kernel<<<nBlocks, 256, 0, stream>>>(sg2, bc_idx, bc_w, Ws2, b2, s2, N);
    stats_kernel<<<64, 256, 0, stream>>>(s2, sums2, sumsq2, N);
    finalize_kernel<<<1, 32, 0, stream>>>(sums2, sumsq2, g2, be2, scale2, shift2, N);

    // ---- residual + relu ----
    final_kernel<<<(N * 8 + 255) / 256, 256, 0, stream>>>(s2, scale2, shift2, signal, out, N * 8);
}